// Round 2
// baseline (460.644 us; speedup 1.0000x reference)
//
#include <hip/hip_runtime.h>
#include <hip/hip_bf16.h>
#include <stdint.h>

#define NN 4096
#define EMB 300
#define KPAD 320

typedef __attribute__((ext_vector_type(8))) short short8;
typedef __attribute__((ext_vector_type(4))) float f32x4;

// ---------------------------------------------------------------------------
// Kernel A: projection  f = l2norm(relu(h@W1+b1)@W2+b2), split to bf16 hi/lo
// 8 rows/block, 1024 blocks, 320 threads (thread = one output column).
// 4 blocks/CU -> 20 waves/CU for latency hiding of the per-k W loads.
// ---------------------------------------------------------------------------
#define PR 8
__global__ __launch_bounds__(320) void proj_kernel(
    const float* __restrict__ h0, const float* __restrict__ h1,
    const float* __restrict__ W1, const float* __restrict__ b1,
    const float* __restrict__ W2, const float* __restrict__ b2,
    unsigned short* __restrict__ f0hi, unsigned short* __restrict__ f0lo,
    unsigned short* __restrict__ f1hi, unsigned short* __restrict__ f1lo)
{
    __shared__ float hs[PR][EMB];
    __shared__ float ys[PR][EMB];
    __shared__ float wred[5][PR];
    __shared__ float scale_s[PR];

    const int tid  = threadIdx.x;
    const int wave = tid >> 6;
    const int lane = tid & 63;
    const int blk  = blockIdx.x;
    const int half = blk >> 9;               // 0 -> h0, 1 -> h1
    const int row0 = (blk & 511) * PR;
    const float* __restrict__ H = half ? h1 : h0;
    unsigned short* __restrict__ FHI = half ? f1hi : f0hi;
    unsigned short* __restrict__ FLO = half ? f1lo : f0lo;

    for (int idx = tid; idx < PR * EMB; idx += 320) {
        int r = idx / EMB, c = idx - r * EMB;
        hs[r][c] = H[(size_t)(row0 + r) * EMB + c];
    }
    __syncthreads();

    const int j = tid;
    float acc[PR];

    if (j < EMB) {                                   // layer 1
        float bb = b1[j];
        #pragma unroll
        for (int r = 0; r < PR; ++r) acc[r] = bb;
        #pragma unroll 4
        for (int k = 0; k < EMB; ++k) {
            float w = W1[(size_t)k * EMB + j];
            #pragma unroll
            for (int r = 0; r < PR; ++r) acc[r] = fmaf(hs[r][k], w, acc[r]);
        }
        #pragma unroll
        for (int r = 0; r < PR; ++r) ys[r][j] = fmaxf(acc[r], 0.f);
    }
    __syncthreads();

    float z[PR];
    #pragma unroll
    for (int r = 0; r < PR; ++r) z[r] = 0.f;
    if (j < EMB) {                                   // layer 2
        float bb = b2[j];
        #pragma unroll
        for (int r = 0; r < PR; ++r) acc[r] = bb;
        #pragma unroll 4
        for (int k = 0; k < EMB; ++k) {
            float w = W2[(size_t)k * EMB + j];
            #pragma unroll
            for (int r = 0; r < PR; ++r) acc[r] = fmaf(ys[r][k], w, acc[r]);
        }
        #pragma unroll
        for (int r = 0; r < PR; ++r) z[r] = acc[r];
    }

    // per-row squared-norm reduce (all threads participate; pad lanes add 0)
    float pz[PR];
    #pragma unroll
    for (int r = 0; r < PR; ++r) pz[r] = z[r] * z[r];
    #pragma unroll
    for (int off = 32; off >= 1; off >>= 1) {
        #pragma unroll
        for (int r = 0; r < PR; ++r) pz[r] += __shfl_down(pz[r], off, 64);
    }
    if (lane == 0) {
        #pragma unroll
        for (int r = 0; r < PR; ++r) wred[wave][r] = pz[r];
    }
    __syncthreads();
    if (tid < PR) {
        float s = 0.f;
        #pragma unroll
        for (int w = 0; w < 5; ++w) s += wred[w][tid];
        scale_s[tid] = 1.0f / fmaxf(sqrtf(s), 1e-12f);
    }
    __syncthreads();

    if (j < EMB) {
        #pragma unroll
        for (int r = 0; r < PR; ++r) {
            float f = z[r] * scale_s[r];
            __hip_bfloat16 hb = __float2bfloat16(f);
            float hf = __bfloat162float(hb);
            __hip_bfloat16 lb = __float2bfloat16(f - hf);
            size_t o = (size_t)(row0 + r) * KPAD + j;
            FHI[o] = *reinterpret_cast<unsigned short*>(&hb);
            FLO[o] = *reinterpret_cast<unsigned short*>(&lb);
        }
    } else {                                          // zero the K-padding
        #pragma unroll
        for (int r = 0; r < PR; ++r) {
            size_t o = (size_t)(row0 + r) * KPAD + j;
            FHI[o] = 0; FLO[o] = 0;
        }
    }
}

// ---------------------------------------------------------------------------
// Kernel B: S0 = exp((f0 f1^T)/T) + eps  via split-bf16 MFMA (hi*hi+hi*lo+lo*hi)
// 128x128 tile, 4 waves (2x2), 16x16x32 MFMA, global_load_lds width-16 staging.
// Epilogue also accumulates column sums (Sinkhorn iteration i=0) into tcol.
// ---------------------------------------------------------------------------
#define BM 128
#define BN 128
#define BK 32

__global__ __launch_bounds__(256) void gemm_exp_kernel(
    const unsigned short* __restrict__ Ahi, const unsigned short* __restrict__ Alo,
    const unsigned short* __restrict__ Bhi, const unsigned short* __restrict__ Blo,
    float* __restrict__ S, float* __restrict__ tcol)
{
    __shared__ unsigned short lA[2][BM * BK];
    __shared__ unsigned short lB[2][BN * BK];
    __shared__ float colsum[BN];

    const int tid  = threadIdx.x;
    const int wave = tid >> 6;
    const int lane = tid & 63;
    const int bx   = blockIdx.x & 31;
    const int by   = blockIdx.x >> 5;
    const int brow = by * BM, bcol = bx * BN;
    const int wm   = wave >> 1, wn = wave & 1;
    const int frow = lane & 15;
    const int kgrp = lane >> 4;

    f32x4 acc[4][4];
    #pragma unroll
    for (int m = 0; m < 4; ++m)
        #pragma unroll
        for (int n = 0; n < 4; ++n) acc[m][n] = (f32x4)0.f;

    // each wave stages one of the 4 buffers
    const unsigned short* gbase = (wave == 0) ? Ahi : (wave == 1) ? Alo
                                 : (wave == 2) ? Bhi : Blo;
    unsigned short* lbase = (wave == 0) ? lA[0] : (wave == 1) ? lA[1]
                           : (wave == 2) ? lB[0] : lB[1];
    const int rb   = (wave < 2) ? brow : bcol;
    const int srow = lane >> 2;          // 0..15
    const int scol = (lane & 3) * 8;     // element offset in K

    for (int kt = 0; kt < KPAD / BK; ++kt) {
        const int k0 = kt * BK;
        __syncthreads();
        #pragma unroll
        for (int c = 0; c < 8; ++c) {
            const unsigned short* g =
                gbase + (size_t)(rb + c * 16 + srow) * KPAD + k0 + scol;
            __builtin_amdgcn_global_load_lds(
                (const __attribute__((address_space(1))) void*)g,
                (__attribute__((address_space(3))) void*)(lbase + c * 512),
                16, 0, 0);
        }
        __syncthreads();

        short8 ahi[4], alo[4], bhi[4], blo[4];
        #pragma unroll
        for (int m = 0; m < 4; ++m) {
            int r = wm * 64 + m * 16 + frow;
            ahi[m] = *(const short8*)(lA[0] + r * BK + kgrp * 8);
            alo[m] = *(const short8*)(lA[1] + r * BK + kgrp * 8);
        }
        #pragma unroll
        for (int n = 0; n < 4; ++n) {
            int r = wn * 64 + n * 16 + frow;
            bhi[n] = *(const short8*)(lB[0] + r * BK + kgrp * 8);
            blo[n] = *(const short8*)(lB[1] + r * BK + kgrp * 8);
        }
        #pragma unroll
        for (int m = 0; m < 4; ++m)
            #pragma unroll
            for (int n = 0; n < 4; ++n) {
                acc[m][n] = __builtin_amdgcn_mfma_f32_16x16x32_bf16(ahi[m], bhi[n], acc[m][n], 0, 0, 0);
                acc[m][n] = __builtin_amdgcn_mfma_f32_16x16x32_bf16(ahi[m], blo[n], acc[m][n], 0, 0, 0);
                acc[m][n] = __builtin_amdgcn_mfma_f32_16x16x32_bf16(alo[m], bhi[n], acc[m][n], 0, 0, 0);
            }
    }

    if (tid < BN) colsum[tid] = 0.f;
    __syncthreads();

    const float SCALE = 36.067376022224085f;  // log2(e)/0.04
    #pragma unroll
    for (int n = 0; n < 4; ++n) {
        const int col = bcol + wn * 64 + n * 16 + frow;
        float cp = 0.f;
        #pragma unroll
        for (int m = 0; m < 4; ++m) {
            const int rbase = brow + wm * 64 + m * 16 + kgrp * 4;
            f32x4 a = acc[m][n];
            #pragma unroll
            for (int q = 0; q < 4; ++q) {
                float sv = exp2f(a[q] * SCALE) + 1e-10f;
                S[(size_t)(rbase + q) * NN + col] = sv;
                cp += sv;
            }
        }
        atomicAdd(&colsum[wn * 64 + n * 16 + frow], cp);
    }
    __syncthreads();
    if (tid < BN) atomicAdd(&tcol[bcol + tid], colsum[tid]);
}

// ---------------------------------------------------------------------------
// Fused Sinkhorn pair:  given v, compute per-row u_i = 1/(S_i . v), and
// accumulate t_j += u_i * S_ij  -- one read of S per (row,col) iteration pair.
// ---------------------------------------------------------------------------
#define RROWS 8
__global__ __launch_bounds__(256) void rowcol_pass(
    const float* __restrict__ S, const float* __restrict__ v, float* __restrict__ t)
{
    __shared__ float vs[NN];
    __shared__ float red[4];
    const int tid = threadIdx.x;
    const int wave = tid >> 6, lane = tid & 63;
    for (int i = tid; i < NN / 4; i += 256)
        ((float4*)vs)[i] = ((const float4*)v)[i];
    __syncthreads();
    const int row0 = blockIdx.x * RROWS;

    float4 tp[4];
    #pragma unroll
    for (int ii = 0; ii < 4; ++ii) tp[ii] = make_float4(0.f, 0.f, 0.f, 0.f);

    for (int rr = 0; rr < RROWS; ++rr) {
        const float4* rowp = (const float4*)(S + (size_t)(row0 + rr) * NN);
        float4 rv[4];
        float part = 0.f;
        #pragma unroll
        for (int ii = 0; ii < 4; ++ii) {
            int c4 = tid + 256 * ii;
            rv[ii] = rowp[c4];
            float4 vv = ((const float4*)vs)[c4];
            part += rv[ii].x * vv.x + rv[ii].y * vv.y + rv[ii].z * vv.z + rv[ii].w * vv.w;
        }
        #pragma unroll
        for (int off = 32; off >= 1; off >>= 1) part += __shfl_down(part, off, 64);
        if (lane == 0) red[wave] = part;
        __syncthreads();
        float ui = 1.0f / (red[0] + red[1] + red[2] + red[3]);
        #pragma unroll
        for (int ii = 0; ii < 4; ++ii) {
            tp[ii].x = fmaf(rv[ii].x, ui, tp[ii].x);
            tp[ii].y = fmaf(rv[ii].y, ui, tp[ii].y);
            tp[ii].z = fmaf(rv[ii].z, ui, tp[ii].z);
            tp[ii].w = fmaf(rv[ii].w, ui, tp[ii].w);
        }
        __syncthreads();
    }
    #pragma unroll
    for (int ii = 0; ii < 4; ++ii) {
        int c = (tid + 256 * ii) * 4;
        atomicAdd(&t[c + 0], tp[ii].x);
        atomicAdd(&t[c + 1], tp[ii].y);
        atomicAdd(&t[c + 2], tp[ii].z);
        atomicAdd(&t[c + 3], tp[ii].w);
    }
}

__global__ __launch_bounds__(256) void fix_kernel(float* __restrict__ t, float* __restrict__ v)
{
    int i = blockIdx.x * 256 + threadIdx.x;
    v[i] = 1.0f / t[i];
    t[i] = 0.f;   // re-zero for the next col accumulation
}

// final: u_i = 1/(row . v); out_ij = u_i * S0_ij * v_j  (in place)
__global__ __launch_bounds__(256) void final_kernel(
    float* __restrict__ S, const float* __restrict__ v)
{
    __shared__ float vs[NN];
    __shared__ float red[4];
    const int tid = threadIdx.x;
    const int wave = tid >> 6, lane = tid & 63;
    for (int i = tid; i < NN / 4; i += 256)
        ((float4*)vs)[i] = ((const float4*)v)[i];
    __syncthreads();
    const int row0 = blockIdx.x * RROWS;
    for (int rr = 0; rr < RROWS; ++rr) {
        float4* rowp = (float4*)(S + (size_t)(row0 + rr) * NN);
        float4 rv[4];
        float part = 0.f;
        #pragma unroll
        for (int ii = 0; ii < 4; ++ii) {
            int c4 = tid + 256 * ii;
            rv[ii] = rowp[c4];
            float4 vv = ((const float4*)vs)[c4];
            part += rv[ii].x * vv.x + rv[ii].y * vv.y + rv[ii].z * vv.z + rv[ii].w * vv.w;
        }
        #pragma unroll
        for (int off = 32; off >= 1; off >>= 1) part += __shfl_down(part, off, 64);
        if (lane == 0) red[wave] = part;
        __syncthreads();
        float ui = 1.0f / (red[0] + red[1] + red[2] + red[3]);
        #pragma unroll
        for (int ii = 0; ii < 4; ++ii) {
            int c4 = tid + 256 * ii;
            float4 vv = ((const float4*)vs)[c4];
            float4 o;
            o.x = rv[ii].x * ui * vv.x;
            o.y = rv[ii].y * ui * vv.y;
            o.z = rv[ii].z * ui * vv.z;
            o.w = rv[ii].w * ui * vv.w;
            rowp[c4] = o;
        }
        __syncthreads();
    }
}

// ---------------------------------------------------------------------------
extern "C" void kernel_launch(void* const* d_in, const int* in_sizes, int n_in,
                              void* d_out, int out_size, void* d_ws, size_t ws_size,
                              hipStream_t stream)
{
    (void)in_sizes; (void)n_in; (void)out_size; (void)ws_size;
    const float* h0 = (const float*)d_in[0];
    const float* h1 = (const float*)d_in[1];
    const float* W1 = (const float*)d_in[2];
    const float* b1 = (const float*)d_in[3];
    const float* W2 = (const float*)d_in[4];
    const float* b2 = (const float*)d_in[5];
    float* S = (float*)d_out;      // S0 lives in the output buffer

    char* ws = (char*)d_ws;
    const size_t FSZ = (size_t)NN * KPAD * sizeof(unsigned short);
    unsigned short* f0hi = (unsigned short*)(ws);
    unsigned short* f0lo = (unsigned short*)(ws + FSZ);
    unsigned short* f1hi = (unsigned short*)(ws + 2 * FSZ);
    unsigned short* f1lo = (unsigned short*)(ws + 3 * FSZ);
    float* v = (float*)(ws + 4 * FSZ);
    float* t = (float*)(ws + 4 * FSZ + NN * sizeof(float));

    hipMemsetAsync(t, 0, NN * sizeof(float), stream);
    proj_kernel<<<1024, 320, 0, stream>>>(h0, h1, W1, b1, W2, b2, f0hi, f0lo, f1hi, f1lo);
    gemm_exp_kernel<<<1024, 256, 0, stream>>>(f0hi, f0lo, f1hi, f1lo, S, t);  // + i=0 colsums
    fix_kernel<<<16, 256, 0, stream>>>(t, v);                                  // v = 1/t
    for (int it = 0; it < 4; ++it) {
        rowcol_pass<<<512, 256, 0, stream>>>(S, v, t);   // i = 1+2, 3+4, 5+6, 7+8
        fix_kernel<<<16, 256, 0, stream>>>(t, v);
    }
    final_kernel<<<512, 256, 0, stream>>>(S, v);          // i = 9 + output write
}

// Round 3
// 336.187 us; speedup vs baseline: 1.3702x; 1.3702x over previous
//
#include <hip/hip_runtime.h>
#include <hip/hip_bf16.h>
#include <stdint.h>

#define NN 4096
#define EMB 300
#define KPAD 320

typedef __attribute__((ext_vector_type(8))) short short8;
typedef __attribute__((ext_vector_type(4))) float f32x4;

__device__ __forceinline__ float bf2f(unsigned short b) {
    return __uint_as_float(((unsigned int)b) << 16);
}

// ---------------------------------------------------------------------------
// Kernel A: projection  f = l2norm(relu(h@W1+b1)@W2+b2), split to bf16 hi/lo
// 8 rows/block, 1024 blocks, 320 threads (thread = one output column).
// ---------------------------------------------------------------------------
#define PR 8
__global__ __launch_bounds__(320) void proj_kernel(
    const float* __restrict__ h0, const float* __restrict__ h1,
    const float* __restrict__ W1, const float* __restrict__ b1,
    const float* __restrict__ W2, const float* __restrict__ b2,
    unsigned short* __restrict__ f0hi, unsigned short* __restrict__ f0lo,
    unsigned short* __restrict__ f1hi, unsigned short* __restrict__ f1lo)
{
    __shared__ float hs[PR][EMB];
    __shared__ float ys[PR][EMB];
    __shared__ float wred[5][PR];
    __shared__ float scale_s[PR];

    const int tid  = threadIdx.x;
    const int wave = tid >> 6;
    const int lane = tid & 63;
    const int blk  = blockIdx.x;
    const int half = blk >> 9;               // 0 -> h0, 1 -> h1
    const int row0 = (blk & 511) * PR;
    const float* __restrict__ H = half ? h1 : h0;
    unsigned short* __restrict__ FHI = half ? f1hi : f0hi;
    unsigned short* __restrict__ FLO = half ? f1lo : f0lo;

    for (int idx = tid; idx < PR * EMB; idx += 320) {
        int r = idx / EMB, c = idx - r * EMB;
        hs[r][c] = H[(size_t)(row0 + r) * EMB + c];
    }
    __syncthreads();

    const int j = tid;
    float acc[PR];

    if (j < EMB) {                                   // layer 1
        float bb = b1[j];
        #pragma unroll
        for (int r = 0; r < PR; ++r) acc[r] = bb;
        #pragma unroll 4
        for (int k = 0; k < EMB; ++k) {
            float w = W1[(size_t)k * EMB + j];
            #pragma unroll
            for (int r = 0; r < PR; ++r) acc[r] = fmaf(hs[r][k], w, acc[r]);
        }
        #pragma unroll
        for (int r = 0; r < PR; ++r) ys[r][j] = fmaxf(acc[r], 0.f);
    }
    __syncthreads();

    float z[PR];
    #pragma unroll
    for (int r = 0; r < PR; ++r) z[r] = 0.f;
    if (j < EMB) {                                   // layer 2
        float bb = b2[j];
        #pragma unroll
        for (int r = 0; r < PR; ++r) acc[r] = bb;
        #pragma unroll 4
        for (int k = 0; k < EMB; ++k) {
            float w = W2[(size_t)k * EMB + j];
            #pragma unroll
            for (int r = 0; r < PR; ++r) acc[r] = fmaf(ys[r][k], w, acc[r]);
        }
        #pragma unroll
        for (int r = 0; r < PR; ++r) z[r] = acc[r];
    }

    float pz[PR];
    #pragma unroll
    for (int r = 0; r < PR; ++r) pz[r] = z[r] * z[r];
    #pragma unroll
    for (int off = 32; off >= 1; off >>= 1) {
        #pragma unroll
        for (int r = 0; r < PR; ++r) pz[r] += __shfl_down(pz[r], off, 64);
    }
    if (lane == 0) {
        #pragma unroll
        for (int r = 0; r < PR; ++r) wred[wave][r] = pz[r];
    }
    __syncthreads();
    if (tid < PR) {
        float s = 0.f;
        #pragma unroll
        for (int w = 0; w < 5; ++w) s += wred[w][tid];
        scale_s[tid] = 1.0f / fmaxf(sqrtf(s), 1e-12f);
    }
    __syncthreads();

    if (j < EMB) {
        #pragma unroll
        for (int r = 0; r < PR; ++r) {
            float f = z[r] * scale_s[r];
            __hip_bfloat16 hb = __float2bfloat16(f);
            float hf = __bfloat162float(hb);
            __hip_bfloat16 lb = __float2bfloat16(f - hf);
            size_t o = (size_t)(row0 + r) * KPAD + j;
            FHI[o] = *reinterpret_cast<unsigned short*>(&hb);
            FLO[o] = *reinterpret_cast<unsigned short*>(&lb);
        }
    } else {
        #pragma unroll
        for (int r = 0; r < PR; ++r) {
            size_t o = (size_t)(row0 + r) * KPAD + j;
            FHI[o] = 0; FLO[o] = 0;
        }
    }
}

// ---------------------------------------------------------------------------
// Kernel B: S0 = exp((f0 f1^T)/T) + eps  via split-bf16 MFMA.
// Writes fp32 S (output buffer), optional bf16 shadow Sb (for Sinkhorn reads),
// and accumulates i=0 column sums into tcol.
// ---------------------------------------------------------------------------
#define BM 128
#define BN 128
#define BK 32

__global__ __launch_bounds__(256) void gemm_exp_kernel(
    const unsigned short* __restrict__ Ahi, const unsigned short* __restrict__ Alo,
    const unsigned short* __restrict__ Bhi, const unsigned short* __restrict__ Blo,
    float* __restrict__ S, unsigned short* __restrict__ Sb, float* __restrict__ tcol)
{
    __shared__ unsigned short lA[2][BM * BK];
    __shared__ unsigned short lB[2][BN * BK];
    __shared__ float colsum[BN];

    const int tid  = threadIdx.x;
    const int wave = tid >> 6;
    const int lane = tid & 63;
    const int bx   = blockIdx.x & 31;
    const int by   = blockIdx.x >> 5;
    const int brow = by * BM, bcol = bx * BN;
    const int wm   = wave >> 1, wn = wave & 1;
    const int frow = lane & 15;
    const int kgrp = lane >> 4;

    f32x4 acc[4][4];
    #pragma unroll
    for (int m = 0; m < 4; ++m)
        #pragma unroll
        for (int n = 0; n < 4; ++n) acc[m][n] = (f32x4)0.f;

    const unsigned short* gbase = (wave == 0) ? Ahi : (wave == 1) ? Alo
                                 : (wave == 2) ? Bhi : Blo;
    unsigned short* lbase = (wave == 0) ? lA[0] : (wave == 1) ? lA[1]
                           : (wave == 2) ? lB[0] : lB[1];
    const int rb   = (wave < 2) ? brow : bcol;
    const int srow = lane >> 2;
    const int scol = (lane & 3) * 8;

    for (int kt = 0; kt < KPAD / BK; ++kt) {
        const int k0 = kt * BK;
        __syncthreads();
        #pragma unroll
        for (int c = 0; c < 8; ++c) {
            const unsigned short* g =
                gbase + (size_t)(rb + c * 16 + srow) * KPAD + k0 + scol;
            __builtin_amdgcn_global_load_lds(
                (const __attribute__((address_space(1))) void*)g,
                (__attribute__((address_space(3))) void*)(lbase + c * 512),
                16, 0, 0);
        }
        __syncthreads();

        short8 ahi[4], alo[4], bhi[4], blo[4];
        #pragma unroll
        for (int m = 0; m < 4; ++m) {
            int r = wm * 64 + m * 16 + frow;
            ahi[m] = *(const short8*)(lA[0] + r * BK + kgrp * 8);
            alo[m] = *(const short8*)(lA[1] + r * BK + kgrp * 8);
        }
        #pragma unroll
        for (int n = 0; n < 4; ++n) {
            int r = wn * 64 + n * 16 + frow;
            bhi[n] = *(const short8*)(lB[0] + r * BK + kgrp * 8);
            blo[n] = *(const short8*)(lB[1] + r * BK + kgrp * 8);
        }
        #pragma unroll
        for (int m = 0; m < 4; ++m)
            #pragma unroll
            for (int n = 0; n < 4; ++n) {
                acc[m][n] = __builtin_amdgcn_mfma_f32_16x16x32_bf16(ahi[m], bhi[n], acc[m][n], 0, 0, 0);
                acc[m][n] = __builtin_amdgcn_mfma_f32_16x16x32_bf16(ahi[m], blo[n], acc[m][n], 0, 0, 0);
                acc[m][n] = __builtin_amdgcn_mfma_f32_16x16x32_bf16(alo[m], bhi[n], acc[m][n], 0, 0, 0);
            }
    }

    if (tid < BN) colsum[tid] = 0.f;
    __syncthreads();

    const float SCALE = 36.067376022224085f;  // log2(e)/0.04
    #pragma unroll
    for (int n = 0; n < 4; ++n) {
        const int col = bcol + wn * 64 + n * 16 + frow;
        float cp = 0.f;
        #pragma unroll
        for (int m = 0; m < 4; ++m) {
            const int rbase = brow + wm * 64 + m * 16 + kgrp * 4;
            f32x4 a = acc[m][n];
            #pragma unroll
            for (int q = 0; q < 4; ++q) {
                float sv = exp2f(a[q] * SCALE) + 1e-10f;
                S[(size_t)(rbase + q) * NN + col] = sv;
                if (Sb) {
                    __hip_bfloat16 sb = __float2bfloat16(sv);
                    Sb[(size_t)(rbase + q) * NN + col] =
                        *reinterpret_cast<unsigned short*>(&sb);
                }
                cp += sv;
            }
        }
        atomicAdd(&colsum[wn * 64 + n * 16 + frow], cp);
    }
    __syncthreads();
    if (tid < BN) atomicAdd(&tcol[bcol + tid], colsum[tid]);
}

// ---------------------------------------------------------------------------
// Sinkhorn passes (s_k = diag(u) S0 diag(v)).  Barrier-free streaming loops.
// ---------------------------------------------------------------------------
#define RROWS 8

// fp32 fallback row pass: u_i = 1/(S_i . v)
__global__ __launch_bounds__(256) void row_pass(
    const float* __restrict__ S, const float* __restrict__ v, float* __restrict__ u)
{
    __shared__ float vs[NN];
    __shared__ float red[RROWS][4];
    const int tid = threadIdx.x;
    const int wave = tid >> 6, lane = tid & 63;
    for (int i = tid; i < NN / 4; i += 256)
        ((float4*)vs)[i] = ((const float4*)v)[i];
    __syncthreads();
    const int row0 = blockIdx.x * RROWS;
    for (int rr = 0; rr < RROWS; ++rr) {
        const float4* rowp = (const float4*)(S + (size_t)(row0 + rr) * NN);
        float part = 0.f;
        #pragma unroll 4
        for (int c4 = tid; c4 < NN / 4; c4 += 256) {
            float4 sv = rowp[c4];
            float4 vv = ((const float4*)vs)[c4];
            part += sv.x * vv.x + sv.y * vv.y + sv.z * vv.z + sv.w * vv.w;
        }
        #pragma unroll
        for (int off = 32; off >= 1; off >>= 1) part += __shfl_down(part, off, 64);
        if (lane == 0) red[rr][wave] = part;
    }
    __syncthreads();
    if (tid < RROWS) {
        float rs = red[tid][0] + red[tid][1] + red[tid][2] + red[tid][3];
        u[row0 + tid] = 1.0f / rs;
    }
}

// bf16 row pass
__global__ __launch_bounds__(256) void row_pass_b16(
    const unsigned short* __restrict__ Sb, const float* __restrict__ v,
    float* __restrict__ u)
{
    __shared__ float vs[NN];
    __shared__ float red[RROWS][4];
    const int tid = threadIdx.x;
    const int wave = tid >> 6, lane = tid & 63;
    for (int i = tid; i < NN / 4; i += 256)
        ((float4*)vs)[i] = ((const float4*)v)[i];
    __syncthreads();
    const int row0 = blockIdx.x * RROWS;
    for (int rr = 0; rr < RROWS; ++rr) {
        const short8* rowp = (const short8*)(Sb + (size_t)(row0 + rr) * NN);
        float part = 0.f;
        #pragma unroll
        for (int ii = 0; ii < 2; ++ii) {
            int c8 = tid + 256 * ii;
            short8 sv8 = rowp[c8];
            #pragma unroll
            for (int e = 0; e < 8; ++e)
                part = fmaf(bf2f((unsigned short)sv8[e]), vs[c8 * 8 + e], part);
        }
        #pragma unroll
        for (int off = 32; off >= 1; off >>= 1) part += __shfl_down(part, off, 64);
        if (lane == 0) red[rr][wave] = part;
    }
    __syncthreads();
    if (tid < RROWS) {
        float rs = red[tid][0] + red[tid][1] + red[tid][2] + red[tid][3];
        u[row0 + tid] = 1.0f / rs;
    }
}

// fp32 fallback col pass: t_j += sum_i u_i S_ij
#define CROWS 32
__global__ __launch_bounds__(256) void col_pass(
    const float* __restrict__ S, const float* __restrict__ u, float* __restrict__ t)
{
    __shared__ float us[CROWS];
    const int tid = threadIdx.x;
    const int cb = blockIdx.x & 3;
    const int rbk = blockIdx.x >> 2;
    const int col0 = cb * 1024 + tid * 4;
    const int row0 = rbk * CROWS;
    if (tid < CROWS) us[tid] = u[row0 + tid];
    __syncthreads();
    float a0 = 0, a1 = 0, a2 = 0, a3 = 0;
    #pragma unroll 8
    for (int r = 0; r < CROWS; ++r) {
        float4 sv = *(const float4*)(S + (size_t)(row0 + r) * NN + col0);
        float ur = us[r];
        a0 = fmaf(sv.x, ur, a0);
        a1 = fmaf(sv.y, ur, a1);
        a2 = fmaf(sv.z, ur, a2);
        a3 = fmaf(sv.w, ur, a3);
    }
    atomicAdd(&t[col0 + 0], a0);
    atomicAdd(&t[col0 + 1], a1);
    atomicAdd(&t[col0 + 2], a2);
    atomicAdd(&t[col0 + 3], a3);
}

// bf16 col pass (8 cols/thread)
__global__ __launch_bounds__(256) void col_pass_b16(
    const unsigned short* __restrict__ Sb, const float* __restrict__ u,
    float* __restrict__ t)
{
    __shared__ float us[CROWS];
    const int tid = threadIdx.x;
    const int cb = blockIdx.x & 1;
    const int rbk = blockIdx.x >> 1;
    const int col0 = cb * 2048 + tid * 8;
    const int row0 = rbk * CROWS;
    if (tid < CROWS) us[tid] = u[row0 + tid];
    __syncthreads();
    float a[8];
    #pragma unroll
    for (int e = 0; e < 8; ++e) a[e] = 0.f;
    #pragma unroll 8
    for (int r = 0; r < CROWS; ++r) {
        short8 sv8 = *(const short8*)(Sb + (size_t)(row0 + r) * NN + col0);
        float ur = us[r];
        #pragma unroll
        for (int e = 0; e < 8; ++e)
            a[e] = fmaf(bf2f((unsigned short)sv8[e]), ur, a[e]);
    }
    #pragma unroll
    for (int e = 0; e < 8; ++e) atomicAdd(&t[col0 + e], a[e]);
}

__global__ __launch_bounds__(256) void fix_kernel(float* __restrict__ t, float* __restrict__ v)
{
    int i = blockIdx.x * 256 + threadIdx.x;
    v[i] = 1.0f / t[i];
    t[i] = 0.f;
}

// final: u_i = 1/(row . v); out_ij = u_i * S0_ij * v_j  (in place)
// Wave-autonomous: each wave owns 2 rows, full row in registers, no barriers.
__global__ __launch_bounds__(256) void final_kernel(
    float* __restrict__ S, const float* __restrict__ v)
{
    __shared__ float vs[NN];
    const int tid = threadIdx.x;
    const int wave = tid >> 6, lane = tid & 63;
    for (int i = tid; i < NN / 4; i += 256)
        ((float4*)vs)[i] = ((const float4*)v)[i];
    __syncthreads();
    const int row0 = blockIdx.x * 8 + wave * 2;
    for (int rr = 0; rr < 2; ++rr) {
        float4* rowp = (float4*)(S + (size_t)(row0 + rr) * NN);
        float4 rv[16];
        #pragma unroll
        for (int ii = 0; ii < 16; ++ii) rv[ii] = rowp[lane + 64 * ii];
        float part = 0.f;
        #pragma unroll
        for (int ii = 0; ii < 16; ++ii) {
            float4 vv = ((const float4*)vs)[lane + 64 * ii];
            part += rv[ii].x * vv.x + rv[ii].y * vv.y + rv[ii].z * vv.z + rv[ii].w * vv.w;
        }
        #pragma unroll
        for (int off = 32; off >= 1; off >>= 1) part += __shfl_down(part, off, 64);
        part = __shfl(part, 0, 64);
        const float ui = 1.0f / part;
        #pragma unroll
        for (int ii = 0; ii < 16; ++ii) {
            int c4 = lane + 64 * ii;
            float4 vv = ((const float4*)vs)[c4];
            float4 o = rv[ii];
            o.x *= ui * vv.x;
            o.y *= ui * vv.y;
            o.z *= ui * vv.z;
            o.w *= ui * vv.w;
            rowp[c4] = o;
        }
    }
}

// ---------------------------------------------------------------------------
extern "C" void kernel_launch(void* const* d_in, const int* in_sizes, int n_in,
                              void* d_out, int out_size, void* d_ws, size_t ws_size,
                              hipStream_t stream)
{
    (void)in_sizes; (void)n_in; (void)out_size;
    const float* h0 = (const float*)d_in[0];
    const float* h1 = (const float*)d_in[1];
    const float* W1 = (const float*)d_in[2];
    const float* b1 = (const float*)d_in[3];
    const float* W2 = (const float*)d_in[4];
    const float* b2 = (const float*)d_in[5];
    float* S = (float*)d_out;

    char* ws = (char*)d_ws;
    const size_t FSZ  = (size_t)NN * KPAD * sizeof(unsigned short);
    const size_t SBSZ = (size_t)NN * NN * sizeof(unsigned short);
    unsigned short* f0hi = (unsigned short*)(ws);
    unsigned short* f0lo = (unsigned short*)(ws + FSZ);
    unsigned short* f1hi = (unsigned short*)(ws + 2 * FSZ);
    unsigned short* f1lo = (unsigned short*)(ws + 3 * FSZ);

    const bool big = ws_size >= 4 * FSZ + SBSZ + 3 * (size_t)NN * sizeof(float);
    unsigned short* Sb = big ? (unsigned short*)(ws + 4 * FSZ) : nullptr;
    char* tail = ws + 4 * FSZ + (big ? SBSZ : 0);
    float* u = (float*)(tail);
    float* v = (float*)(tail + NN * sizeof(float));
    float* t = (float*)(tail + 2 * NN * sizeof(float));

    hipMemsetAsync(t, 0, NN * sizeof(float), stream);
    proj_kernel<<<1024, 320, 0, stream>>>(h0, h1, W1, b1, W2, b2, f0hi, f0lo, f1hi, f1lo);
    gemm_exp_kernel<<<1024, 256, 0, stream>>>(f0hi, f0lo, f1hi, f1lo, S, Sb, t);
    fix_kernel<<<16, 256, 0, stream>>>(t, v);                    // v = 1/colsum (i=0)
    for (int it = 0; it < 4; ++it) {                              // i = 1..8
        if (big) {
            row_pass_b16<<<512, 256, 0, stream>>>(Sb, v, u);
            col_pass_b16<<<256, 256, 0, stream>>>(Sb, u, t);
        } else {
            row_pass<<<512, 256, 0, stream>>>(S, v, u);
            col_pass<<<512, 256, 0, stream>>>(S, u, t);
        }
        fix_kernel<<<16, 256, 0, stream>>>(t, v);
    }
    final_kernel<<<512, 256, 0, stream>>>(S, v);                  // i = 9 + write
}

// Round 4
// 314.753 us; speedup vs baseline: 1.4635x; 1.0681x over previous
//
#include <hip/hip_runtime.h>
#include <hip/hip_bf16.h>
#include <stdint.h>

#define NN 4096
#define EMB 300
#define KPAD 320          // padded K for all GEMMs (=KP)
#define KP  320
#define NPAD 384          // padded N for MLP weight tiles (3 x 128)

typedef __attribute__((ext_vector_type(8))) short short8;
typedef __attribute__((ext_vector_type(4))) float f32x4;

__device__ __forceinline__ float bf2f(unsigned short b) {
    return __uint_as_float(((unsigned int)b) << 16);
}
__device__ __forceinline__ void split_store(float f, unsigned short* hi, unsigned short* lo) {
    __hip_bfloat16 hb = __float2bfloat16(f);
    float hf = __bfloat162float(hb);
    __hip_bfloat16 lb = __float2bfloat16(f - hf);
    *hi = *reinterpret_cast<unsigned short*>(&hb);
    *lo = *reinterpret_cast<unsigned short*>(&lb);
}

// ---------------------------------------------------------------------------
// split_h: h0,h1 [4096x300] fp32 -> Hhi/Hlo [8192x320] bf16 (zero K-pad)
// ---------------------------------------------------------------------------
__global__ __launch_bounds__(320) void split_h_kernel(
    const float* __restrict__ h0, const float* __restrict__ h1,
    unsigned short* __restrict__ Hhi, unsigned short* __restrict__ Hlo)
{
    const int j = threadIdx.x;
    const int row0 = blockIdx.x * 8;
    for (int r = 0; r < 8; ++r) {
        int row = row0 + r;
        float v = 0.f;
        if (j < EMB)
            v = (row < NN) ? h0[(size_t)row * EMB + j]
                           : h1[(size_t)(row - NN) * EMB + j];
        size_t o = (size_t)row * KP + j;
        split_store(v, &Hhi[o], &Hlo[o]);
    }
}

// ---------------------------------------------------------------------------
// wsplit: W1,W2 [300x300] -> W1t/W2t hi/lo [384x320] (transposed, padded);
// also pads b1,b2 to [384].
// ---------------------------------------------------------------------------
__global__ __launch_bounds__(256) void wsplit_kernel(
    const float* __restrict__ W1, const float* __restrict__ W2,
    const float* __restrict__ b1, const float* __restrict__ b2,
    unsigned short* __restrict__ W1th, unsigned short* __restrict__ W1tl,
    unsigned short* __restrict__ W2th, unsigned short* __restrict__ W2tl,
    float* __restrict__ b1p, float* __restrict__ b2p)
{
    const int blk = blockIdx.x;
    const int tid = threadIdx.x;
    const int which = (blk >= 480);
    const int i = (blk - (which ? 480 : 0)) * 256 + tid;   // 0..122879
    const int n = i / KP, k = i - n * KP;
    const float* W = which ? W2 : W1;
    unsigned short* Wh = which ? W2th : W1th;
    unsigned short* Wl = which ? W2tl : W1tl;
    float val = (n < EMB && k < EMB) ? W[(size_t)k * EMB + n] : 0.f;
    split_store(val, &Wh[i], &Wl[i]);
    if (blk == 0) {
        for (int x = tid; x < NPAD; x += 256) {
            b1p[x] = (x < EMB) ? b1[x] : 0.f;
            b2p[x] = (x < EMB) ? b2[x] : 0.f;
        }
    }
}

// ---------------------------------------------------------------------------
// Shared MFMA tile machinery (proven gemm structure): 128x128 tile, 4 waves,
// split-bf16 (hi*hi + hi*lo + lo*hi), K=320 (10 iters of BK=32).
// ---------------------------------------------------------------------------
#define BM 128
#define BN 128
#define BK 32

#define GEMM_CORE(Ahi_, Alo_, Bhi_, Blo_)                                      \
    __shared__ unsigned short lA[2][BM * BK];                                  \
    __shared__ unsigned short lB[2][BN * BK];                                  \
    const int tid  = threadIdx.x;                                              \
    const int wave = tid >> 6;                                                 \
    const int lane = tid & 63;                                                 \
    const int wm   = wave >> 1, wn = wave & 1;                                 \
    const int frow = lane & 15;                                                \
    const int kgrp = lane >> 4;                                                \
    f32x4 acc[4][4];                                                           \
    _Pragma("unroll")                                                          \
    for (int m = 0; m < 4; ++m)                                                \
        _Pragma("unroll")                                                      \
        for (int n = 0; n < 4; ++n) acc[m][n] = (f32x4)0.f;                    \
    const unsigned short* gbase = (wave == 0) ? Ahi_ : (wave == 1) ? Alo_      \
                                 : (wave == 2) ? Bhi_ : Blo_;                  \
    unsigned short* lbase = (wave == 0) ? lA[0] : (wave == 1) ? lA[1]          \
                           : (wave == 2) ? lB[0] : lB[1];                      \
    const int rb   = (wave < 2) ? brow : bcol;                                 \
    const int srow = lane >> 2;                                                \
    const int scol = (lane & 3) * 8;                                           \
    for (int kt = 0; kt < KP / BK; ++kt) {                                     \
        const int k0 = kt * BK;                                                \
        __syncthreads();                                                       \
        _Pragma("unroll")                                                      \
        for (int c = 0; c < 8; ++c) {                                          \
            const unsigned short* g =                                          \
                gbase + (size_t)(rb + c * 16 + srow) * KP + k0 + scol;         \
            __builtin_amdgcn_global_load_lds(                                  \
                (const __attribute__((address_space(1))) void*)g,              \
                (__attribute__((address_space(3))) void*)(lbase + c * 512),    \
                16, 0, 0);                                                     \
        }                                                                      \
        __syncthreads();                                                       \
        short8 ahi[4], alo[4], bhi[4], blo[4];                                 \
        _Pragma("unroll")                                                      \
        for (int m = 0; m < 4; ++m) {                                          \
            int r = wm * 64 + m * 16 + frow;                                   \
            ahi[m] = *(const short8*)(lA[0] + r * BK + kgrp * 8);              \
            alo[m] = *(const short8*)(lA[1] + r * BK + kgrp * 8);              \
        }                                                                      \
        _Pragma("unroll")                                                      \
        for (int n = 0; n < 4; ++n) {                                          \
            int r = wn * 64 + n * 16 + frow;                                   \
            bhi[n] = *(const short8*)(lB[0] + r * BK + kgrp * 8);              \
            blo[n] = *(const short8*)(lB[1] + r * BK + kgrp * 8);              \
        }                                                                      \
        _Pragma("unroll")                                                      \
        for (int m = 0; m < 4; ++m)                                            \
            _Pragma("unroll")                                                  \
            for (int n = 0; n < 4; ++n) {                                      \
                acc[m][n] = __builtin_amdgcn_mfma_f32_16x16x32_bf16(ahi[m], bhi[n], acc[m][n], 0, 0, 0); \
                acc[m][n] = __builtin_amdgcn_mfma_f32_16x16x32_bf16(ahi[m], blo[n], acc[m][n], 0, 0, 0); \
                acc[m][n] = __builtin_amdgcn_mfma_f32_16x16x32_bf16(alo[m], bhi[n], acc[m][n], 0, 0, 0); \
            }                                                                  \
    }

// ---------------------------------------------------------------------------
// gemm_l1: Y = split( relu( H @ W1t^T + b1 ) )   grid 64x3 = 192 blocks
// ---------------------------------------------------------------------------
__global__ __launch_bounds__(256) void gemm_l1_kernel(
    const unsigned short* __restrict__ Ahi, const unsigned short* __restrict__ Alo,
    const unsigned short* __restrict__ Bhi, const unsigned short* __restrict__ Blo,
    const float* __restrict__ b1p,
    unsigned short* __restrict__ Yhi, unsigned short* __restrict__ Ylo)
{
    const int bx = blockIdx.x % 3;
    const int by = blockIdx.x / 3;
    const int brow = by * BM, bcol = bx * BN;
    GEMM_CORE(Ahi, Alo, Bhi, Blo)

    #pragma unroll
    for (int n = 0; n < 4; ++n) {
        const int col = bcol + wn * 64 + n * 16 + frow;
        const float bb = b1p[col];
        const bool ok = col < KP;
        #pragma unroll
        for (int m = 0; m < 4; ++m) {
            const int rbase = brow + wm * 64 + m * 16 + kgrp * 4;
            f32x4 a = acc[m][n];
            #pragma unroll
            for (int q = 0; q < 4; ++q) {
                if (ok) {
                    float y = fmaxf(a[q] + bb, 0.f);
                    size_t o = (size_t)(rbase + q) * KP + col;
                    split_store(y, &Yhi[o], &Ylo[o]);
                }
            }
        }
    }
}

// ---------------------------------------------------------------------------
// gemm_l2: Z = Y @ W2t^T + b2  (fp32), and rowssq[row] += sum_j Z^2 (atomics)
// ---------------------------------------------------------------------------
__global__ __launch_bounds__(256) void gemm_l2_kernel(
    const unsigned short* __restrict__ Ahi, const unsigned short* __restrict__ Alo,
    const unsigned short* __restrict__ Bhi, const unsigned short* __restrict__ Blo,
    const float* __restrict__ b2p,
    float* __restrict__ Z, float* __restrict__ rowssq)
{
    const int bx = blockIdx.x % 3;
    const int by = blockIdx.x / 3;
    const int brow = by * BM, bcol = bx * BN;
    GEMM_CORE(Ahi, Alo, Bhi, Blo)

    float sq[4][4];
    #pragma unroll
    for (int m = 0; m < 4; ++m)
        #pragma unroll
        for (int q = 0; q < 4; ++q) sq[m][q] = 0.f;

    #pragma unroll
    for (int n = 0; n < 4; ++n) {
        const int col = bcol + wn * 64 + n * 16 + frow;
        const float bb = b2p[col];
        const bool ok = col < KP;
        #pragma unroll
        for (int m = 0; m < 4; ++m) {
            const int rbase = brow + wm * 64 + m * 16 + kgrp * 4;
            f32x4 a = acc[m][n];
            #pragma unroll
            for (int q = 0; q < 4; ++q) {
                float z = a[q] + bb;            // pad cols: acc=0,bb=0 -> z=0
                if (ok) Z[(size_t)(rbase + q) * KP + col] = z;
                sq[m][q] = fmaf(z, z, sq[m][q]);
            }
        }
    }
    // reduce sq over the 16 frow lanes (same kgrp group), then one atomic/row
    #pragma unroll
    for (int m = 0; m < 4; ++m)
        #pragma unroll
        for (int q = 0; q < 4; ++q) {
            float v2 = sq[m][q];
            #pragma unroll
            for (int off = 1; off <= 8; off <<= 1) v2 += __shfl_xor(v2, off, 64);
            if ((lane & 15) == 0)
                atomicAdd(&rowssq[brow + wm * 64 + m * 16 + kgrp * 4 + q], v2);
        }
}

// ---------------------------------------------------------------------------
// normalize: f = Z * rsqrt-row-norm, split to Fhi/Flo [8192x320]
// ---------------------------------------------------------------------------
__global__ __launch_bounds__(320) void normalize_kernel(
    const float* __restrict__ Z, const float* __restrict__ rowssq,
    unsigned short* __restrict__ Fhi, unsigned short* __restrict__ Flo)
{
    const int j = threadIdx.x;
    const int row0 = blockIdx.x * 8;
    for (int r = 0; r < 8; ++r) {
        int row = row0 + r;
        float sc = 1.0f / fmaxf(sqrtf(rowssq[row]), 1e-12f);
        size_t o = (size_t)row * KP + j;
        split_store(Z[o] * sc, &Fhi[o], &Flo[o]);
    }
}

// ---------------------------------------------------------------------------
// gemm_exp: S0 = exp((f0 f1^T)/T) + eps ; writes fp32 S, bf16 Sb, i=0 colsums
// ---------------------------------------------------------------------------
__global__ __launch_bounds__(256) void gemm_exp_kernel(
    const unsigned short* __restrict__ Ahi, const unsigned short* __restrict__ Alo,
    const unsigned short* __restrict__ Bhi, const unsigned short* __restrict__ Blo,
    float* __restrict__ S, unsigned short* __restrict__ Sb, float* __restrict__ tcol)
{
    __shared__ float colsum[BN];
    const int bx = blockIdx.x & 31;
    const int by = blockIdx.x >> 5;
    const int brow = by * BM, bcol = bx * BN;
    GEMM_CORE(Ahi, Alo, Bhi, Blo)

    if (tid < BN) colsum[tid] = 0.f;
    __syncthreads();

    const float SCALE = 36.067376022224085f;  // log2(e)/0.04
    #pragma unroll
    for (int n = 0; n < 4; ++n) {
        const int col = bcol + wn * 64 + n * 16 + frow;
        float cp = 0.f;
        #pragma unroll
        for (int m = 0; m < 4; ++m) {
            const int rbase = brow + wm * 64 + m * 16 + kgrp * 4;
            f32x4 a = acc[m][n];
            #pragma unroll
            for (int q = 0; q < 4; ++q) {
                float sv = exp2f(a[q] * SCALE) + 1e-10f;
                S[(size_t)(rbase + q) * NN + col] = sv;
                if (Sb) {
                    __hip_bfloat16 sb = __float2bfloat16(sv);
                    Sb[(size_t)(rbase + q) * NN + col] =
                        *reinterpret_cast<unsigned short*>(&sb);
                }
                cp += sv;
            }
        }
        atomicAdd(&colsum[wn * 64 + n * 16 + frow], cp);
    }
    __syncthreads();
    if (tid < BN) atomicAdd(&tcol[bcol + tid], colsum[tid]);
}

// ---------------------------------------------------------------------------
// Sinkhorn passes (barrier-free streaming)
// ---------------------------------------------------------------------------
#define RROWS 8
__global__ __launch_bounds__(256) void row_pass(
    const float* __restrict__ S, const float* __restrict__ v, float* __restrict__ u)
{
    __shared__ float vs[NN];
    __shared__ float red[RROWS][4];
    const int tid = threadIdx.x;
    const int wave = tid >> 6, lane = tid & 63;
    for (int i = tid; i < NN / 4; i += 256)
        ((float4*)vs)[i] = ((const float4*)v)[i];
    __syncthreads();
    const int row0 = blockIdx.x * RROWS;
    for (int rr = 0; rr < RROWS; ++rr) {
        const float4* rowp = (const float4*)(S + (size_t)(row0 + rr) * NN);
        float part = 0.f;
        #pragma unroll 4
        for (int c4 = tid; c4 < NN / 4; c4 += 256) {
            float4 sv = rowp[c4];
            float4 vv = ((const float4*)vs)[c4];
            part += sv.x * vv.x + sv.y * vv.y + sv.z * vv.z + sv.w * vv.w;
        }
        #pragma unroll
        for (int off = 32; off >= 1; off >>= 1) part += __shfl_down(part, off, 64);
        if (lane == 0) red[rr][wave] = part;
    }
    __syncthreads();
    if (tid < RROWS) {
        float rs = red[tid][0] + red[tid][1] + red[tid][2] + red[tid][3];
        u[row0 + tid] = 1.0f / rs;
    }
}

__global__ __launch_bounds__(256) void row_pass_b16(
    const unsigned short* __restrict__ Sb, const float* __restrict__ v,
    float* __restrict__ u)
{
    __shared__ float vs[NN];
    __shared__ float red[RROWS][4];
    const int tid = threadIdx.x;
    const int wave = tid >> 6, lane = tid & 63;
    for (int i = tid; i < NN / 4; i += 256)
        ((float4*)vs)[i] = ((const float4*)v)[i];
    __syncthreads();
    const int row0 = blockIdx.x * RROWS;
    for (int rr = 0; rr < RROWS; ++rr) {
        const short8* rowp = (const short8*)(Sb + (size_t)(row0 + rr) * NN);
        float part = 0.f;
        #pragma unroll
        for (int ii = 0; ii < 2; ++ii) {
            int c8 = tid + 256 * ii;
            short8 sv8 = rowp[c8];
            #pragma unroll
            for (int e = 0; e < 8; ++e)
                part = fmaf(bf2f((unsigned short)sv8[e]), vs[c8 * 8 + e], part);
        }
        #pragma unroll
        for (int off = 32; off >= 1; off >>= 1) part += __shfl_down(part, off, 64);
        if (lane == 0) red[rr][wave] = part;
    }
    __syncthreads();
    if (tid < RROWS) {
        float rs = red[tid][0] + red[tid][1] + red[tid][2] + red[tid][3];
        u[row0 + tid] = 1.0f / rs;
    }
}

#define CROWS 32
__global__ __launch_bounds__(256) void col_pass(
    const float* __restrict__ S, const float* __restrict__ u, float* __restrict__ t)
{
    __shared__ float us[CROWS];
    const int tid = threadIdx.x;
    const int cb = blockIdx.x & 3;
    const int rbk = blockIdx.x >> 2;
    const int col0 = cb * 1024 + tid * 4;
    const int row0 = rbk * CROWS;
    if (tid < CROWS) us[tid] = u[row0 + tid];
    __syncthreads();
    float a0 = 0, a1 = 0, a2 = 0, a3 = 0;
    #pragma unroll 8
    for (int r = 0; r < CROWS; ++r) {
        float4 sv = *(const float4*)(S + (size_t)(row0 + r) * NN + col0);
        float ur = us[r];
        a0 = fmaf(sv.x, ur, a0);
        a1 = fmaf(sv.y, ur, a1);
        a2 = fmaf(sv.z, ur, a2);
        a3 = fmaf(sv.w, ur, a3);
    }
    atomicAdd(&t[col0 + 0], a0);
    atomicAdd(&t[col0 + 1], a1);
    atomicAdd(&t[col0 + 2], a2);
    atomicAdd(&t[col0 + 3], a3);
}

__global__ __launch_bounds__(256) void col_pass_b16(
    const unsigned short* __restrict__ Sb, const float* __restrict__ u,
    float* __restrict__ t)
{
    __shared__ float us[CROWS];
    const int tid = threadIdx.x;
    const int cb = blockIdx.x & 1;
    const int rbk = blockIdx.x >> 1;
    const int col0 = cb * 2048 + tid * 8;
    const int row0 = rbk * CROWS;
    if (tid < CROWS) us[tid] = u[row0 + tid];
    __syncthreads();
    float a[8];
    #pragma unroll
    for (int e = 0; e < 8; ++e) a[e] = 0.f;
    #pragma unroll 8
    for (int r = 0; r < CROWS; ++r) {
        short8 sv8 = *(const short8*)(Sb + (size_t)(row0 + r) * NN + col0);
        float ur = us[r];
        #pragma unroll
        for (int e = 0; e < 8; ++e)
            a[e] = fmaf(bf2f((unsigned short)sv8[e]), ur, a[e]);
    }
    #pragma unroll
    for (int e = 0; e < 8; ++e) atomicAdd(&t[col0 + e], a[e]);
}

__global__ __launch_bounds__(256) void fix_kernel(float* __restrict__ t, float* __restrict__ v)
{
    int i = blockIdx.x * 256 + threadIdx.x;
    v[i] = 1.0f / t[i];
    t[i] = 0.f;
}

// final: u_i = 1/(row . v); out_ij = u_i * S0_ij * v_j  (in place, wave-autonomous)
__global__ __launch_bounds__(256) void final_kernel(
    float* __restrict__ S, const float* __restrict__ v)
{
    __shared__ float vs[NN];
    const int tid = threadIdx.x;
    const int wave = tid >> 6, lane = tid & 63;
    for (int i = tid; i < NN / 4; i += 256)
        ((float4*)vs)[i] = ((const float4*)v)[i];
    __syncthreads();
    const int row0 = blockIdx.x * 8 + wave * 2;
    for (int rr = 0; rr < 2; ++rr) {
        float4* rowp = (float4*)(S + (size_t)(row0 + rr) * NN);
        float4 rv[16];
        #pragma unroll
        for (int ii = 0; ii < 16; ++ii) rv[ii] = rowp[lane + 64 * ii];
        float part = 0.f;
        #pragma unroll
        for (int ii = 0; ii < 16; ++ii) {
            float4 vv = ((const float4*)vs)[lane + 64 * ii];
            part += rv[ii].x * vv.x + rv[ii].y * vv.y + rv[ii].z * vv.z + rv[ii].w * vv.w;
        }
        #pragma unroll
        for (int off = 32; off >= 1; off >>= 1) part += __shfl_down(part, off, 64);
        part = __shfl(part, 0, 64);
        const float ui = 1.0f / part;
        #pragma unroll
        for (int ii = 0; ii < 16; ++ii) {
            int c4 = lane + 64 * ii;
            float4 vv = ((const float4*)vs)[c4];
            float4 o = rv[ii];
            o.x *= ui * vv.x;
            o.y *= ui * vv.y;
            o.z *= ui * vv.z;
            o.w *= ui * vv.w;
            rowp[c4] = o;
        }
    }
}

// ---------------------------------------------------------------------------
extern "C" void kernel_launch(void* const* d_in, const int* in_sizes, int n_in,
                              void* d_out, int out_size, void* d_ws, size_t ws_size,
                              hipStream_t stream)
{
    (void)in_sizes; (void)n_in; (void)out_size;
    const float* h0 = (const float*)d_in[0];
    const float* h1 = (const float*)d_in[1];
    const float* W1 = (const float*)d_in[2];
    const float* b1 = (const float*)d_in[3];
    const float* W2 = (const float*)d_in[4];
    const float* b2 = (const float*)d_in[5];
    float* S = (float*)d_out;

    // ---- workspace: Fhi/Flo (both halves), Sb, vectors ----
    char* ws = (char*)d_ws;
    const size_t FROW = (size_t)2 * NN * KP;          // 8192 x 320 elements
    const size_t FSZB = FROW * sizeof(unsigned short);
    unsigned short* Fhi = (unsigned short*)(ws);
    unsigned short* Flo = (unsigned short*)(ws + FSZB);
    const size_t SBSZ = (size_t)NN * NN * sizeof(unsigned short);
    const bool big = ws_size >= 2 * FSZB + SBSZ + 3 * (size_t)NN * sizeof(float);
    unsigned short* Sb = big ? (unsigned short*)(ws + 2 * FSZB) : nullptr;
    char* tail = ws + 2 * FSZB + (big ? SBSZ : 0);
    float* u = (float*)(tail);
    float* v = (float*)(tail + NN * sizeof(float));
    float* t = (float*)(tail + 2 * NN * sizeof(float));

    // ---- transient scratch inside d_out (dead until gemm_exp rewrites S) ----
    unsigned short* us = (unsigned short*)d_out;
    unsigned short* Hhi = us;
    unsigned short* Hlo = us + FROW;
    unsigned short* Yhi = us + 2 * FROW;
    unsigned short* Ylo = us + 3 * FROW;
    const size_t WSZ = (size_t)NPAD * KP;             // 384*320
    unsigned short* W1th = us + 4 * FROW;
    unsigned short* W1tl = W1th + WSZ;
    unsigned short* W2th = W1tl + WSZ;
    unsigned short* W2tl = W2th + WSZ;
    char* zb = (char*)(W2tl + WSZ);
    float* Z      = (float*)zb;                       // 8192 x 320 fp32
    float* rowssq = (float*)(zb + FROW * sizeof(float));
    float* b1p    = rowssq + 2 * NN;
    float* b2p    = b1p + NPAD;

    hipMemsetAsync(t, 0, NN * sizeof(float), stream);
    hipMemsetAsync(rowssq, 0, 2 * NN * sizeof(float), stream);

    split_h_kernel<<<1024, 320, 0, stream>>>(h0, h1, Hhi, Hlo);
    wsplit_kernel<<<960, 256, 0, stream>>>(W1, W2, b1, b2,
                                           W1th, W1tl, W2th, W2tl, b1p, b2p);
    gemm_l1_kernel<<<192, 256, 0, stream>>>(Hhi, Hlo, W1th, W1tl, b1p, Yhi, Ylo);
    gemm_l2_kernel<<<192, 256, 0, stream>>>(Yhi, Ylo, W2th, W2tl, b2p, Z, rowssq);
    normalize_kernel<<<1024, 320, 0, stream>>>(Z, rowssq, Fhi, Flo);

    // f0 = rows 0..4095, f1 = rows 4096..8191
    gemm_exp_kernel<<<1024, 256, 0, stream>>>(
        Fhi, Flo, Fhi + (size_t)NN * KP, Flo + (size_t)NN * KP, S, Sb, t);
    fix_kernel<<<16, 256, 0, stream>>>(t, v);                    // v = 1/colsum (i=0)
    for (int it = 0; it < 4; ++it) {                              // i = 1..8
        if (big) {
            row_pass_b16<<<512, 256, 0, stream>>>(Sb, v, u);
            col_pass_b16<<<256, 256, 0, stream>>>(Sb, u, t);
        } else {
            row_pass<<<512, 256, 0, stream>>>(S, v, u);
            col_pass<<<512, 256, 0, stream>>>(S, u, t);
        }
        fix_kernel<<<16, 256, 0, stream>>>(t, v);
    }
    final_kernel<<<512, 256, 0, stream>>>(S, v);                  // i = 9 + write
}